// Round 1
// baseline (181.396 us; speedup 1.0000x reference)
//
#include <hip/hip_runtime.h>

#define BB 32
#define NN 256
#define DIN 512
#define DD 256
#define HH 512
#define MM 8192      // BB*NN
#define NDG 65536    // NN*DD
#define KSTR 16

// ---------------- K1: xie = xi @ W_img + b_img  (8192x512 @ 512x256) ----------
__global__ __launch_bounds__(256) void k_enc(const float* __restrict__ A,
                                             const float* __restrict__ W,
                                             const float* __restrict__ bias,
                                             float* __restrict__ C) {
  __shared__ float As[16][68];
  __shared__ float Bs[16][68];
  const int tid = threadIdx.x;
  const int m0 = blockIdx.x * 64, n0 = blockIdx.y * 64;
  const int tx = tid & 15, ty = tid >> 4;
  const int lrow = tid >> 2, lfc = (tid & 3) * 4;
  float acc[4][4] = {};
  for (int k0 = 0; k0 < DIN; k0 += 16) {
    float4 va = *reinterpret_cast<const float4*>(&A[(m0 + lrow) * DIN + k0 + lfc]);
    As[lfc + 0][lrow] = va.x; As[lfc + 1][lrow] = va.y;
    As[lfc + 2][lrow] = va.z; As[lfc + 3][lrow] = va.w;
    const int bk = tid >> 4, bn = (tid & 15) * 4;
    *reinterpret_cast<float4*>(&Bs[bk][bn]) =
        *reinterpret_cast<const float4*>(&W[(k0 + bk) * DD + n0 + bn]);
    __syncthreads();
#pragma unroll
    for (int kk = 0; kk < 16; ++kk) {
      float a[4], b[4];
      *reinterpret_cast<float4*>(a) = *reinterpret_cast<float4*>(&As[kk][ty * 4]);
      *reinterpret_cast<float4*>(b) = *reinterpret_cast<float4*>(&Bs[kk][tx * 4]);
#pragma unroll
      for (int i = 0; i < 4; ++i)
#pragma unroll
        for (int j = 0; j < 4; ++j) acc[i][j] += a[i] * b[j];
    }
    __syncthreads();
  }
#pragma unroll
  for (int i = 0; i < 4; ++i) {
    const int m = m0 + ty * 4 + i;
    float4 v;
    v.x = acc[i][0] + bias[n0 + tx * 4 + 0];
    v.y = acc[i][1] + bias[n0 + tx * 4 + 1];
    v.z = acc[i][2] + bias[n0 + tx * 4 + 2];
    v.w = acc[i][3] + bias[n0 + tx * 4 + 3];
    *reinterpret_cast<float4*>(&C[m * DD + n0 + tx * 4]) = v;
  }
}

// ---------------- K1b: row norms x2[i] = sum(xie[i,:]^2) ----------------------
__global__ __launch_bounds__(256) void k_norm(const float* __restrict__ X,
                                              float* __restrict__ x2) {
  const int tid = threadIdx.x;
  const int row = blockIdx.x * 4 + (tid >> 6);
  const int lane = tid & 63;
  float4 v = *reinterpret_cast<const float4*>(&X[row * DD + lane * 4]);
  float s = v.x * v.x + v.y * v.y + v.z * v.z + v.w * v.w;
#pragma unroll
  for (int off = 1; off < 64; off <<= 1) s += __shfl_xor(s, off);
  if (lane == 0) x2[row] = s;
}

// ---------------- K2a: d2[b][n][m] = x2n + x2m - 2*<xn,xm>, diag=1e30 ---------
__global__ __launch_bounds__(256) void k_dist(const float* __restrict__ X,
                                              const float* __restrict__ x2,
                                              float* __restrict__ d2) {
  __shared__ float As[16][68];
  __shared__ float Bs[16][68];
  const int tid = threadIdx.x;
  const int b = blockIdx.z;
  const int m0 = blockIdx.x * 64, n0 = blockIdx.y * 64;
  const float* Xb = X + b * NN * DD;
  const int tx = tid & 15, ty = tid >> 4;
  const int lrow = tid >> 2, lfc = (tid & 3) * 4;
  float acc[4][4] = {};
  for (int k0 = 0; k0 < DD; k0 += 16) {
    float4 va = *reinterpret_cast<const float4*>(&Xb[(n0 + lrow) * DD + k0 + lfc]);
    As[lfc + 0][lrow] = va.x; As[lfc + 1][lrow] = va.y;
    As[lfc + 2][lrow] = va.z; As[lfc + 3][lrow] = va.w;
    float4 vb = *reinterpret_cast<const float4*>(&Xb[(m0 + lrow) * DD + k0 + lfc]);
    Bs[lfc + 0][lrow] = vb.x; Bs[lfc + 1][lrow] = vb.y;
    Bs[lfc + 2][lrow] = vb.z; Bs[lfc + 3][lrow] = vb.w;
    __syncthreads();
#pragma unroll
    for (int kk = 0; kk < 16; ++kk) {
      float a[4], bv[4];
      *reinterpret_cast<float4*>(a) = *reinterpret_cast<float4*>(&As[kk][ty * 4]);
      *reinterpret_cast<float4*>(bv) = *reinterpret_cast<float4*>(&Bs[kk][tx * 4]);
#pragma unroll
      for (int i = 0; i < 4; ++i)
#pragma unroll
        for (int j = 0; j < 4; ++j) acc[i][j] += a[i] * bv[j];
    }
    __syncthreads();
  }
#pragma unroll
  for (int i = 0; i < 4; ++i) {
    const int n = n0 + ty * 4 + i;
    const float xn = x2[b * NN + n];
    float4 v;
    float* vv = reinterpret_cast<float*>(&v);
#pragma unroll
    for (int j = 0; j < 4; ++j) {
      const int mc = m0 + tx * 4 + j;
      float dv = xn + x2[b * NN + mc] - 2.0f * acc[i][j];
      if (n == mc) dv = 1e30f;
      vv[j] = dv;
    }
    *reinterpret_cast<float4*>(&d2[(b * NN + n) * NN + m0 + tx * 4]) = v;
  }
}

// ---------------- K2b: per-row top-k (smallest d2, ties -> smaller index) -----
__global__ __launch_bounds__(256) void k_topk(const float* __restrict__ d2,
                                              const int* __restrict__ kp,
                                              int* __restrict__ nbr) {
  const int tid = threadIdx.x;
  const int i = blockIdx.x * 4 + (tid >> 6);
  const int lane = tid & 63;
  const int kcnt = kp[0];
  const float* row = d2 + (size_t)i * NN;
  float v0 = row[lane];
  float v1 = row[lane + 64];
  float v2 = row[lane + 128];
  float v3 = row[lane + 192];
  for (int it = 0; it < kcnt; ++it) {
    float v = v0; int idx = lane;
    if (v1 < v) { v = v1; idx = lane + 64; }
    if (v2 < v) { v = v2; idx = lane + 128; }
    if (v3 < v) { v = v3; idx = lane + 192; }
#pragma unroll
    for (int off = 1; off < 64; off <<= 1) {
      float ov = __shfl_xor(v, off);
      int oi = __shfl_xor(idx, off);
      if (ov < v || (ov == v && oi < idx)) { v = ov; idx = oi; }
    }
    if (lane == 0) nbr[i * KSTR + it] = idx;
    const int slot = idx >> 6;
    if (lane == (idx & 63)) {
      if (slot == 0) v0 = 3e38f;
      else if (slot == 1) v1 = 3e38f;
      else if (slot == 2) v2 = 3e38f;
      else v3 = 3e38f;
    }
  }
}

// ---------------- K3: agg[i,:] = mean over k neighbors of xie ------------------
__global__ __launch_bounds__(256) void k_agg(const float* __restrict__ X,
                                             const int* __restrict__ nbr,
                                             const int* __restrict__ kp,
                                             float* __restrict__ agg) {
  const int i = blockIdx.x;
  const int b = i >> 8;
  const int t = threadIdx.x;
  const int kcnt = kp[0];
  float acc = 0.0f;
  for (int j = 0; j < kcnt; ++j) {
    const int nb = nbr[i * KSTR + j];
    acc += X[(b * NN + nb) * DD + t];
  }
  agg[i * DD + t] = acc / (float)kcnt;
}

// ---------------- K4: gep = relu(xie@Ws + agg@Wn + b_gnn) ---------------------
__global__ __launch_bounds__(256) void k_gnn(const float* __restrict__ A1,
                                             const float* __restrict__ A2,
                                             const float* __restrict__ Ws,
                                             const float* __restrict__ Wn,
                                             const float* __restrict__ bias,
                                             float* __restrict__ C) {
  __shared__ float As[16][68];
  __shared__ float Bs[16][68];
  const int tid = threadIdx.x;
  const int m0 = blockIdx.x * 64, n0 = blockIdx.y * 64;
  const int tx = tid & 15, ty = tid >> 4;
  const int lrow = tid >> 2, lfc = (tid & 3) * 4;
  float acc[4][4] = {};
  for (int ph = 0; ph < 2; ++ph) {
    const float* Ap = ph ? A2 : A1;
    const float* Wp = ph ? Wn : Ws;
    for (int k0 = 0; k0 < DD; k0 += 16) {
      float4 va = *reinterpret_cast<const float4*>(&Ap[(m0 + lrow) * DD + k0 + lfc]);
      As[lfc + 0][lrow] = va.x; As[lfc + 1][lrow] = va.y;
      As[lfc + 2][lrow] = va.z; As[lfc + 3][lrow] = va.w;
      const int bk = tid >> 4, bn = (tid & 15) * 4;
      *reinterpret_cast<float4*>(&Bs[bk][bn]) =
          *reinterpret_cast<const float4*>(&Wp[(k0 + bk) * DD + n0 + bn]);
      __syncthreads();
#pragma unroll
      for (int kk = 0; kk < 16; ++kk) {
        float a[4], bv[4];
        *reinterpret_cast<float4*>(a) = *reinterpret_cast<float4*>(&As[kk][ty * 4]);
        *reinterpret_cast<float4*>(bv) = *reinterpret_cast<float4*>(&Bs[kk][tx * 4]);
#pragma unroll
        for (int i = 0; i < 4; ++i)
#pragma unroll
          for (int j = 0; j < 4; ++j) acc[i][j] += a[i] * bv[j];
      }
      __syncthreads();
    }
  }
#pragma unroll
  for (int i = 0; i < 4; ++i) {
    const int m = m0 + ty * 4 + i;
    float4 v;
    float* vv = reinterpret_cast<float*>(&v);
#pragma unroll
    for (int j = 0; j < 4; ++j) {
      float t = acc[i][j] + bias[n0 + tx * 4 + j];
      vv[j] = t > 0.0f ? t : 0.0f;
    }
    *reinterpret_cast<float4*>(&C[m * DD + n0 + tx * 4]) = v;
  }
}

// ---------------- K5: partial GEMM h_part = gep_flat[32,65536] @ W1 -----------
// grid (8 col-tiles of 64, 64 k-chunks of 1024). Lane owns 8 rows x 4 cols,
// 4-way k-interleave within the wave, reduced by shfl at the end.
__global__ __launch_bounds__(256) void k_mlp1(const float* __restrict__ Aflat,
                                              const float* __restrict__ W1,
                                              float* __restrict__ part) {
  __shared__ float As[256][33];
  const int tid = threadIdx.x;
  const int c0 = blockIdx.x * 64;
  const int k0 = blockIdx.y * 1024;
  const int cg = tid & 15;
  const int ks = (tid >> 4) & 3;
  const int rg = tid >> 6;
  float acc[8][4] = {};
  for (int stage = 0; stage < 4; ++stage) {
    const int kb = k0 + stage * 256;
#pragma unroll
    for (int i = 0; i < 8; ++i) {
      const int j = tid + i * 256;      // float4 id within 32x256 tile
      const int m = j >> 6;
      const int kpos = (j & 63) * 4;
      float4 v = *reinterpret_cast<const float4*>(&Aflat[m * NDG + kb + kpos]);
      As[kpos + 0][m] = v.x; As[kpos + 1][m] = v.y;
      As[kpos + 2][m] = v.z; As[kpos + 3][m] = v.w;
    }
    __syncthreads();
#pragma unroll 4
    for (int t = 0; t < 64; ++t) {
      const int kk = t * 4 + ks;
      const float4 w = *reinterpret_cast<const float4*>(&W1[(size_t)(kb + kk) * HH + c0 + cg * 4]);
#pragma unroll
      for (int r = 0; r < 8; ++r) {
        const float a = As[kk][rg * 8 + r];
        acc[r][0] += a * w.x; acc[r][1] += a * w.y;
        acc[r][2] += a * w.z; acc[r][3] += a * w.w;
      }
    }
    __syncthreads();
  }
#pragma unroll
  for (int r = 0; r < 8; ++r)
#pragma unroll
    for (int c = 0; c < 4; ++c) {
      float v = acc[r][c];
      v += __shfl_xor(v, 16);
      v += __shfl_xor(v, 32);
      acc[r][c] = v;
    }
  if (ks == 0) {
    const int chunk = blockIdx.y;
#pragma unroll
    for (int r = 0; r < 8; ++r) {
      const int m = rg * 8 + r;
      *reinterpret_cast<float4*>(&part[(size_t)(chunk * 32 + m) * HH + c0 + cg * 4]) =
          *reinterpret_cast<float4*>(acc[r]);
    }
  }
}

// ---------------- K5b: h = relu(sum_chunks part + b1) -------------------------
__global__ __launch_bounds__(256) void k_mlp1r(const float* __restrict__ part,
                                               const float* __restrict__ b1,
                                               float* __restrict__ h) {
  const int id = blockIdx.x * 256 + threadIdx.x;   // 0..16383
  const int m = id >> 9, c = id & 511;
  float s = 0.0f;
  for (int ch = 0; ch < 64; ++ch) s += part[(size_t)(ch * 32 + m) * HH + c];
  s += b1[c];
  h[m * HH + c] = s > 0.0f ? s : 0.0f;
}

// ---------------- K6: out = h @ W2 + b2 ---------------------------------------
__global__ __launch_bounds__(256) void k_out(const float* __restrict__ h,
                                             const float* __restrict__ W2,
                                             const float* __restrict__ b2,
                                             float* __restrict__ outp) {
  const int tid = threadIdx.x;
  const int m = blockIdx.x * 4 + (tid >> 6);
  const int lane = tid & 63;
  float s = 0.0f;
#pragma unroll
  for (int j = 0; j < 8; ++j) s += h[m * HH + lane + 64 * j] * W2[lane + 64 * j];
#pragma unroll
  for (int off = 1; off < 64; off <<= 1) s += __shfl_xor(s, off);
  if (lane == 0) outp[m] = s + b2[0];
}

extern "C" void kernel_launch(void* const* d_in, const int* in_sizes, int n_in,
                              void* d_out, int out_size, void* d_ws, size_t ws_size,
                              hipStream_t stream) {
  const float* xi     = (const float*)d_in[0];
  const float* W_img  = (const float*)d_in[1];
  const float* b_img  = (const float*)d_in[2];
  const float* W_self = (const float*)d_in[3];
  const float* W_nbr  = (const float*)d_in[4];
  const float* b_gnn  = (const float*)d_in[5];
  const float* W1     = (const float*)d_in[6];
  const float* b1     = (const float*)d_in[7];
  const float* W2     = (const float*)d_in[8];
  const float* b2     = (const float*)d_in[9];
  const int*   kp     = (const int*)d_in[10];

  float* xie  = (float*)d_out;
  float* gep  = xie + (size_t)MM * DD;
  float* outp = gep + (size_t)MM * DD;

  float* ws   = (float*)d_ws;
  float* x2   = ws;                          // 8192
  int*   nbr  = (int*)(ws + MM);             // 8192*16 ints
  float* agg  = ws + MM + MM * KSTR;         // 8192*256
  float* d2   = agg + (size_t)MM * DD;       // 8192*256
  float* part = d2;                          // reuse d2 region (dead after topk)
  float* hbuf = d2 + (size_t)64 * 32 * HH;   // 32*512

  k_enc  <<<dim3(128, 4), 256, 0, stream>>>(xi, W_img, b_img, xie);
  k_norm <<<MM / 4, 256, 0, stream>>>(xie, x2);
  k_dist <<<dim3(4, 4, BB), 256, 0, stream>>>(xie, x2, d2);
  k_topk <<<MM / 4, 256, 0, stream>>>(d2, kp, nbr);
  k_agg  <<<MM, 256, 0, stream>>>(xie, nbr, kp, agg);
  k_gnn  <<<dim3(128, 4), 256, 0, stream>>>(xie, agg, W_self, W_nbr, b_gnn, gep);
  k_mlp1 <<<dim3(8, 64), 256, 0, stream>>>(gep, W1, part);
  k_mlp1r<<<64, 256, 0, stream>>>(part, b1, hbuf);
  k_out  <<<8, 256, 0, stream>>>(hbuf, W2, b2, outp);
}

// Round 2
// 167.102 us; speedup vs baseline: 1.0855x; 1.0855x over previous
//
#include <hip/hip_runtime.h>

#define BB 32
#define NN 256
#define DIN 512
#define DD 256
#define HH 512
#define MM 8192      // BB*NN
#define NDG 65536    // NN*DD
#define KSTR 16

typedef __attribute__((ext_vector_type(8))) __bf16 bf16x8;
typedef __attribute__((ext_vector_type(4))) float f32x4;

__device__ __forceinline__ unsigned short f2bf(float x) {
  unsigned u = __float_as_uint(x);
  u += 0x7FFFu + ((u >> 16) & 1u);   // round-to-nearest-even
  return (unsigned short)(u >> 16);
}

// ---------------- K1: xie = xi @ W_img + b_img  (8192x512 @ 512x256) ----------
__global__ __launch_bounds__(256) void k_enc(const float* __restrict__ A,
                                             const float* __restrict__ W,
                                             const float* __restrict__ bias,
                                             float* __restrict__ C) {
  __shared__ float As[16][68];
  __shared__ float Bs[16][68];
  const int tid = threadIdx.x;
  const int m0 = blockIdx.x * 64, n0 = blockIdx.y * 64;
  const int tx = tid & 15, ty = tid >> 4;
  const int lrow = tid >> 2, lfc = (tid & 3) * 4;
  float acc[4][4] = {};
  for (int k0 = 0; k0 < DIN; k0 += 16) {
    float4 va = *reinterpret_cast<const float4*>(&A[(m0 + lrow) * DIN + k0 + lfc]);
    As[lfc + 0][lrow] = va.x; As[lfc + 1][lrow] = va.y;
    As[lfc + 2][lrow] = va.z; As[lfc + 3][lrow] = va.w;
    const int bk = tid >> 4, bn = (tid & 15) * 4;
    *reinterpret_cast<float4*>(&Bs[bk][bn]) =
        *reinterpret_cast<const float4*>(&W[(k0 + bk) * DD + n0 + bn]);
    __syncthreads();
#pragma unroll
    for (int kk = 0; kk < 16; ++kk) {
      float a[4], b[4];
      *reinterpret_cast<float4*>(a) = *reinterpret_cast<float4*>(&As[kk][ty * 4]);
      *reinterpret_cast<float4*>(b) = *reinterpret_cast<float4*>(&Bs[kk][tx * 4]);
#pragma unroll
      for (int i = 0; i < 4; ++i)
#pragma unroll
        for (int j = 0; j < 4; ++j) acc[i][j] += a[i] * b[j];
    }
    __syncthreads();
  }
#pragma unroll
  for (int i = 0; i < 4; ++i) {
    const int m = m0 + ty * 4 + i;
    float4 v;
    v.x = acc[i][0] + bias[n0 + tx * 4 + 0];
    v.y = acc[i][1] + bias[n0 + tx * 4 + 1];
    v.z = acc[i][2] + bias[n0 + tx * 4 + 2];
    v.w = acc[i][3] + bias[n0 + tx * 4 + 3];
    *reinterpret_cast<float4*>(&C[m * DD + n0 + tx * 4]) = v;
  }
}

// ---------------- K1b: row norms ----------------------------------------------
__global__ __launch_bounds__(256) void k_norm(const float* __restrict__ X,
                                              float* __restrict__ x2) {
  const int tid = threadIdx.x;
  const int row = blockIdx.x * 4 + (tid >> 6);
  const int lane = tid & 63;
  float4 v = *reinterpret_cast<const float4*>(&X[row * DD + lane * 4]);
  float s = v.x * v.x + v.y * v.y + v.z * v.z + v.w * v.w;
#pragma unroll
  for (int off = 1; off < 64; off <<= 1) s += __shfl_xor(s, off);
  if (lane == 0) x2[row] = s;
}

// ---------------- K2a: pairwise d2 --------------------------------------------
__global__ __launch_bounds__(256) void k_dist(const float* __restrict__ X,
                                              const float* __restrict__ x2,
                                              float* __restrict__ d2) {
  __shared__ float As[16][68];
  __shared__ float Bs[16][68];
  const int tid = threadIdx.x;
  const int b = blockIdx.z;
  const int m0 = blockIdx.x * 64, n0 = blockIdx.y * 64;
  const float* Xb = X + b * NN * DD;
  const int tx = tid & 15, ty = tid >> 4;
  const int lrow = tid >> 2, lfc = (tid & 3) * 4;
  float acc[4][4] = {};
  for (int k0 = 0; k0 < DD; k0 += 16) {
    float4 va = *reinterpret_cast<const float4*>(&Xb[(n0 + lrow) * DD + k0 + lfc]);
    As[lfc + 0][lrow] = va.x; As[lfc + 1][lrow] = va.y;
    As[lfc + 2][lrow] = va.z; As[lfc + 3][lrow] = va.w;
    float4 vb = *reinterpret_cast<const float4*>(&Xb[(m0 + lrow) * DD + k0 + lfc]);
    Bs[lfc + 0][lrow] = vb.x; Bs[lfc + 1][lrow] = vb.y;
    Bs[lfc + 2][lrow] = vb.z; Bs[lfc + 3][lrow] = vb.w;
    __syncthreads();
#pragma unroll
    for (int kk = 0; kk < 16; ++kk) {
      float a[4], bv[4];
      *reinterpret_cast<float4*>(a) = *reinterpret_cast<float4*>(&As[kk][ty * 4]);
      *reinterpret_cast<float4*>(bv) = *reinterpret_cast<float4*>(&Bs[kk][tx * 4]);
#pragma unroll
      for (int i = 0; i < 4; ++i)
#pragma unroll
        for (int j = 0; j < 4; ++j) acc[i][j] += a[i] * bv[j];
    }
    __syncthreads();
  }
#pragma unroll
  for (int i = 0; i < 4; ++i) {
    const int n = n0 + ty * 4 + i;
    const float xn = x2[b * NN + n];
    float4 v;
    float* vv = reinterpret_cast<float*>(&v);
#pragma unroll
    for (int j = 0; j < 4; ++j) {
      const int mc = m0 + tx * 4 + j;
      float dv = xn + x2[b * NN + mc] - 2.0f * acc[i][j];
      if (n == mc) dv = 1e30f;
      vv[j] = dv;
    }
    *reinterpret_cast<float4*>(&d2[(b * NN + n) * NN + m0 + tx * 4]) = v;
  }
}

// ---------------- K2b: per-row top-k ------------------------------------------
__global__ __launch_bounds__(256) void k_topk(const float* __restrict__ d2,
                                              const int* __restrict__ kp,
                                              int* __restrict__ nbr) {
  const int tid = threadIdx.x;
  const int i = blockIdx.x * 4 + (tid >> 6);
  const int lane = tid & 63;
  const int kcnt = kp[0];
  const float* row = d2 + (size_t)i * NN;
  float v0 = row[lane];
  float v1 = row[lane + 64];
  float v2 = row[lane + 128];
  float v3 = row[lane + 192];
  for (int it = 0; it < kcnt; ++it) {
    float v = v0; int idx = lane;
    if (v1 < v) { v = v1; idx = lane + 64; }
    if (v2 < v) { v = v2; idx = lane + 128; }
    if (v3 < v) { v = v3; idx = lane + 192; }
#pragma unroll
    for (int off = 1; off < 64; off <<= 1) {
      float ov = __shfl_xor(v, off);
      int oi = __shfl_xor(idx, off);
      if (ov < v || (ov == v && oi < idx)) { v = ov; idx = oi; }
    }
    if (lane == 0) nbr[i * KSTR + it] = idx;
    const int slot = idx >> 6;
    if (lane == (idx & 63)) {
      if (slot == 0) v0 = 3e38f;
      else if (slot == 1) v1 = 3e38f;
      else if (slot == 2) v2 = 3e38f;
      else v3 = 3e38f;
    }
  }
}

// ---------------- K3: agg (bf16, written into packed A_bf cols 256..511) ------
__global__ __launch_bounds__(256) void k_agg(const float* __restrict__ X,
                                             const int* __restrict__ nbr,
                                             const int* __restrict__ kp,
                                             unsigned short* __restrict__ A_bf) {
  const int i = blockIdx.x;
  const int b = i >> 8;
  const int t = threadIdx.x;
  const int kcnt = kp[0];
  float acc = 0.0f;
  for (int j = 0; j < kcnt; ++j) {
    const int nb = nbr[i * KSTR + j];
    acc += X[(b * NN + nb) * DD + t];
  }
  A_bf[(size_t)i * 512 + 256 + t] = f2bf(acc / (float)kcnt);
}

// ---------------- cvt: xie -> bf16 into A_bf cols 0..255 ----------------------
__global__ __launch_bounds__(256) void k_cvtx(const float* __restrict__ X,
                                              unsigned short* __restrict__ A_bf) {
  const int qid = blockIdx.x * 256 + threadIdx.x;   // 0 .. 8192*64-1
  const int m = qid >> 6;
  const int dq = (qid & 63) * 4;
  float4 v = *reinterpret_cast<const float4*>(&X[(size_t)m * DD + dq]);
  ushort4 o;
  o.x = f2bf(v.x); o.y = f2bf(v.y); o.z = f2bf(v.z); o.w = f2bf(v.w);
  *reinterpret_cast<ushort4*>(&A_bf[(size_t)m * 512 + dq]) = o;
}

// ---------------- cvt: [Ws;Wn] -> bf16 transposed B_bfT[n][k] -----------------
__global__ __launch_bounds__(256) void k_cvtw(const float* __restrict__ Ws,
                                              const float* __restrict__ Wn,
                                              unsigned short* __restrict__ B_bfT) {
  const int id = blockIdx.x * 256 + threadIdx.x;    // 0 .. 131071
  const int k = id >> 8;
  const int n = id & 255;
  float v = (k < 256) ? Ws[k * 256 + n] : Wn[(k - 256) * 256 + n];
  B_bfT[(size_t)n * 512 + k] = f2bf(v);
}

// ---------------- K4: gep = relu(A_bf @ B_bfT^T + b) via bf16 MFMA ------------
// A_bf [8192][512] bf16, B_bfT [256][512] bf16 (n-major). BM=BN=BK=64, 4 waves.
__global__ __launch_bounds__(256) void k_gnn(const unsigned short* __restrict__ A_bf,
                                             const unsigned short* __restrict__ B_bfT,
                                             const float* __restrict__ bias,
                                             float* __restrict__ C) {
  __shared__ unsigned short As[64 * 72];
  __shared__ unsigned short Bs[64 * 72];
  const int tid = threadIdx.x;
  const int m0 = blockIdx.x * 64, n0 = blockIdx.y * 64;
  const int l = tid & 63, w = tid >> 6;
  const int mw = (w & 1) * 32, nw = (w >> 1) * 32;
  const int lr = tid >> 3, lq = tid & 7;        // staging: row, quad-of-8
  f32x4 acc[2][2] = {};
  for (int kt = 0; kt < 8; ++kt) {
    const int kb = kt * 64;
#pragma unroll
    for (int s = 0; s < 2; ++s) {
      const int r = lr + s * 32;
      uint4 va = *reinterpret_cast<const uint4*>(&A_bf[(size_t)(m0 + r) * 512 + kb + lq * 8]);
      *reinterpret_cast<uint4*>(&As[r * 72 + lq * 8]) = va;
      uint4 vb = *reinterpret_cast<const uint4*>(&B_bfT[(size_t)(n0 + r) * 512 + kb + lq * 8]);
      *reinterpret_cast<uint4*>(&Bs[r * 72 + lq * 8]) = vb;
    }
    __syncthreads();
#pragma unroll
    for (int ks = 0; ks < 2; ++ks) {
      bf16x8 af[2], bf[2];
#pragma unroll
      for (int mi = 0; mi < 2; ++mi)
        af[mi] = *reinterpret_cast<const bf16x8*>(
            &As[(mw + mi * 16 + (l & 15)) * 72 + ks * 32 + (l >> 4) * 8]);
#pragma unroll
      for (int ni = 0; ni < 2; ++ni)
        bf[ni] = *reinterpret_cast<const bf16x8*>(
            &Bs[(nw + ni * 16 + (l & 15)) * 72 + ks * 32 + (l >> 4) * 8]);
#pragma unroll
      for (int mi = 0; mi < 2; ++mi)
#pragma unroll
        for (int ni = 0; ni < 2; ++ni)
          acc[mi][ni] = __builtin_amdgcn_mfma_f32_16x16x32_bf16(af[mi], bf[ni],
                                                                acc[mi][ni], 0, 0, 0);
    }
    __syncthreads();
  }
#pragma unroll
  for (int mi = 0; mi < 2; ++mi) {
    const int row_base = m0 + mw + mi * 16 + (l >> 4) * 4;
#pragma unroll
    for (int ni = 0; ni < 2; ++ni) {
      const int col = n0 + nw + ni * 16 + (l & 15);
      const float bv = bias[col];
#pragma unroll
      for (int r = 0; r < 4; ++r) {
        float v = acc[mi][ni][r] + bv;
        C[(size_t)(row_base + r) * 256 + col] = v > 0.0f ? v : 0.0f;
      }
    }
  }
}

// ---------------- K5: h partials = gep_flat[32,65536] @ W1, k-chunked ---------
// 256 blocks x 512 threads. Block b owns k in [b*256, b*256+256).
// LDS A stored [k][m] (32 floats/k) -> conflict-free b128 broadcast reads.
// Thread: col-quad cq=tid&127 (4 cols), team=tid>>7 (k subset), acc[32 rows]x4.
__global__ __launch_bounds__(512) void k_mlp1(const float* __restrict__ A,   // gep
                                              const float* __restrict__ W1,
                                              float* __restrict__ part) {
  __shared__ float lds[8192];                 // 32 KB: 2 halves x 128k x 32m
  const int tid = threadIdx.x;
  const int b = blockIdx.x;
  const int k0 = b * 256;
  const int team = tid >> 7;
  const int cq = tid & 127;
  float4 acc[32];
#pragma unroll
  for (int m = 0; m < 32; ++m) acc[m] = make_float4(0.f, 0.f, 0.f, 0.f);

  // stage half h (128 k-rows) into lds[h*4096 ..]
  auto STAGE = [&](int h) {
#pragma unroll
    for (int i = 0; i < 2; ++i) {
      int q = tid + i * 512;                  // 0..1023
      int m = q >> 5;                         // 32 quads per row
      int kq = q & 31;
      float4 v = *reinterpret_cast<const float4*>(
          &A[(size_t)m * 65536 + k0 + h * 128 + kq * 4]);
      float* dst = &lds[h * 4096 + (kq * 4) * 32 + m];
      dst[0] = v.x; dst[32] = v.y; dst[64] = v.z; dst[96] = v.w;
    }
  };

  STAGE(0);
  __syncthreads();
  STAGE(1);

  for (int h = 0; h < 2; ++h) {
    if (h == 1) __syncthreads();
    const int kk0 = team * 32;
    const size_t wbase = ((size_t)(k0 + h * 128 + kk0)) * 512 + cq * 4;
    float4 wA = *reinterpret_cast<const float4*>(&W1[wbase]);
    float4 wB = *reinterpret_cast<const float4*>(&W1[wbase + 512]);
    for (int i = 0; i < 32; i += 2) {
      float4 wC, wD;
      if (i + 2 < 32) {
        wC = *reinterpret_cast<const float4*>(&W1[wbase + (size_t)(i + 2) * 512]);
        wD = *reinterpret_cast<const float4*>(&W1[wbase + (size_t)(i + 3) * 512]);
      }
      const float4* A4a = reinterpret_cast<const float4*>(&lds[h * 4096 + (kk0 + i) * 32]);
      const float4* A4b = reinterpret_cast<const float4*>(&lds[h * 4096 + (kk0 + i + 1) * 32]);
#pragma unroll
      for (int m8 = 0; m8 < 8; ++m8) {
        float4 av = A4a[m8];
        acc[m8 * 4 + 0].x += av.x * wA.x; acc[m8 * 4 + 0].y += av.x * wA.y;
        acc[m8 * 4 + 0].z += av.x * wA.z; acc[m8 * 4 + 0].w += av.x * wA.w;
        acc[m8 * 4 + 1].x += av.y * wA.x; acc[m8 * 4 + 1].y += av.y * wA.y;
        acc[m8 * 4 + 1].z += av.y * wA.z; acc[m8 * 4 + 1].w += av.y * wA.w;
        acc[m8 * 4 + 2].x += av.z * wA.x; acc[m8 * 4 + 2].y += av.z * wA.y;
        acc[m8 * 4 + 2].z += av.z * wA.z; acc[m8 * 4 + 2].w += av.z * wA.w;
        acc[m8 * 4 + 3].x += av.w * wA.x; acc[m8 * 4 + 3].y += av.w * wA.y;
        acc[m8 * 4 + 3].z += av.w * wA.z; acc[m8 * 4 + 3].w += av.w * wA.w;
      }
#pragma unroll
      for (int m8 = 0; m8 < 8; ++m8) {
        float4 av = A4b[m8];
        acc[m8 * 4 + 0].x += av.x * wB.x; acc[m8 * 4 + 0].y += av.x * wB.y;
        acc[m8 * 4 + 0].z += av.x * wB.z; acc[m8 * 4 + 0].w += av.x * wB.w;
        acc[m8 * 4 + 1].x += av.y * wB.x; acc[m8 * 4 + 1].y += av.y * wB.y;
        acc[m8 * 4 + 1].z += av.y * wB.z; acc[m8 * 4 + 1].w += av.y * wB.w;
        acc[m8 * 4 + 2].x += av.z * wB.x; acc[m8 * 4 + 2].y += av.z * wB.y;
        acc[m8 * 4 + 2].z += av.z * wB.z; acc[m8 * 4 + 2].w += av.z * wB.w;
        acc[m8 * 4 + 3].x += av.w * wB.x; acc[m8 * 4 + 3].y += av.w * wB.y;
        acc[m8 * 4 + 3].z += av.w * wB.z; acc[m8 * 4 + 3].w += av.w * wB.w;
      }
      wA = wC; wB = wD;
    }
  }

  // reduce 4 teams -> team 0, write part[b][32][512]
  float4* lds4 = reinterpret_cast<float4*>(lds);
  for (int rg = 0; rg < 8; ++rg) {
    __syncthreads();
    if (team > 0) {
#pragma unroll
      for (int r = 0; r < 4; ++r)
        lds4[(team - 1) * 512 + r * 128 + cq] = acc[rg * 4 + r];
    }
    __syncthreads();
    if (team == 0) {
#pragma unroll
      for (int r = 0; r < 4; ++r) {
        float4 s = acc[rg * 4 + r];
        float4 p0 = lds4[r * 128 + cq];
        float4 p1 = lds4[512 + r * 128 + cq];
        float4 p2 = lds4[1024 + r * 128 + cq];
        s.x += p0.x + p1.x + p2.x; s.y += p0.y + p1.y + p2.y;
        s.z += p0.z + p1.z + p2.z; s.w += p0.w + p1.w + p2.w;
        *reinterpret_cast<float4*>(
            &part[((size_t)b * 32 + rg * 4 + r) * 512 + cq * 4]) = s;
      }
    }
  }
}

// ---------------- K5b: h = relu(sum_b part + b1) ------------------------------
// 256 blocks x 256 thr. Block: m = blk>>3, c0 = (blk&7)*64. Wave = b-quarter.
__global__ __launch_bounds__(256) void k_mlp1r(const float* __restrict__ part,
                                               const float* __restrict__ b1,
                                               float* __restrict__ h) {
  __shared__ float red[3][64];
  const int tid = threadIdx.x;
  const int m = blockIdx.x >> 3;
  const int c = (blockIdx.x & 7) * 64 + (tid & 63);
  const int bq = tid >> 6;
  float s = 0.0f;
  for (int bb = bq * 64; bb < bq * 64 + 64; ++bb)
    s += part[((size_t)bb * 32 + m) * 512 + c];
  if (bq > 0) red[bq - 1][tid & 63] = s;
  __syncthreads();
  if (bq == 0) {
    s += red[0][tid & 63] + red[1][tid & 63] + red[2][tid & 63];
    s += b1[c];
    h[m * HH + c] = s > 0.0f ? s : 0.0f;
  }
}

// ---------------- K6: out = h @ W2 + b2 ---------------------------------------
__global__ __launch_bounds__(256) void k_out(const float* __restrict__ h,
                                             const float* __restrict__ W2,
                                             const float* __restrict__ b2,
                                             float* __restrict__ outp) {
  const int tid = threadIdx.x;
  const int m = blockIdx.x * 4 + (tid >> 6);
  const int lane = tid & 63;
  float s = 0.0f;
#pragma unroll
  for (int j = 0; j < 8; ++j) s += h[m * HH + lane + 64 * j] * W2[lane + 64 * j];
#pragma unroll
  for (int off = 1; off < 64; off <<= 1) s += __shfl_xor(s, off);
  if (lane == 0) outp[m] = s + b2[0];
}

extern "C" void kernel_launch(void* const* d_in, const int* in_sizes, int n_in,
                              void* d_out, int out_size, void* d_ws, size_t ws_size,
                              hipStream_t stream) {
  const float* xi     = (const float*)d_in[0];
  const float* W_img  = (const float*)d_in[1];
  const float* b_img  = (const float*)d_in[2];
  const float* W_self = (const float*)d_in[3];
  const float* W_nbr  = (const float*)d_in[4];
  const float* b_gnn  = (const float*)d_in[5];
  const float* W1     = (const float*)d_in[6];
  const float* b1     = (const float*)d_in[7];
  const float* W2     = (const float*)d_in[8];
  const float* b2     = (const float*)d_in[9];
  const int*   kp     = (const int*)d_in[10];

  float* xie  = (float*)d_out;
  float* gep  = xie + (size_t)MM * DD;
  float* outp = gep + (size_t)MM * DD;

  float* ws   = (float*)d_ws;
  float* x2   = ws;                                   // 8192
  int*   nbr  = (int*)(ws + MM);                      // 131072 ints
  float* d2   = ws + MM + MM * KSTR;                  // 8192*256
  float* part = d2 + (size_t)MM * DD;                 // 256*32*512
  float* hbuf = part + (size_t)256 * 32 * HH;         // 32*512
  unsigned short* A_bf  = (unsigned short*)(hbuf + BB * HH);  // 8192*512 bf16
  unsigned short* B_bfT = A_bf + (size_t)MM * 512;            // 256*512 bf16

  k_enc  <<<dim3(128, 4), 256, 0, stream>>>(xi, W_img, b_img, xie);
  k_cvtw <<<512, 256, 0, stream>>>(W_self, W_nbr, B_bfT);
  k_norm <<<MM / 4, 256, 0, stream>>>(xie, x2);
  k_dist <<<dim3(4, 4, BB), 256, 0, stream>>>(xie, x2, d2);
  k_topk <<<MM / 4, 256, 0, stream>>>(d2, kp, nbr);
  k_cvtx <<<2048, 256, 0, stream>>>(xie, A_bf);
  k_agg  <<<MM, 256, 0, stream>>>(xie, nbr, kp, A_bf);
  k_gnn  <<<dim3(128, 4), 256, 0, stream>>>(A_bf, B_bfT, b_gnn, gep);
  k_mlp1 <<<256, 512, 0, stream>>>(gep, W1, part);
  k_mlp1r<<<256, 256, 0, stream>>>(part, b1, hbuf);
  k_out  <<<8, 256, 0, stream>>>(hbuf, W2, b2, outp);
}